// Round 21
// baseline (126.774 us; speedup 1.0000x reference)
//
#include <hip/hip_runtime.h>
#include <hip/hip_bf16.h>

// GraphConv x2 via dst-sorted CSR gather.
// CSR build with ZERO global returning atomics (LDS-atomic 4-phase).
// R21: CSHIFT 7->6 (p4 grid 782->1563 blocks; R19 lesson: small grids starve),
// scan_k3 folded into p3/p4 (bsums added at offset-load time), -1 launch.
// node_mfma: node transform on matrix cores. gather2 v4: 4 nodes x 16 lanes.

#define NF 64
#define CSHIFT 6
#define CMASK 63
#define CMAX 2048   // supports N <= 131072

typedef __attribute__((ext_vector_type(8))) short bf16x8;
typedef __attribute__((ext_vector_type(4))) float f32x4;

__device__ __forceinline__ unsigned short f2bf(float f) {
    __hip_bfloat16 h = __float2bfloat16(f);
    return *reinterpret_cast<unsigned short*>(&h);
}
__device__ __forceinline__ float bf2f(unsigned short u) {
    return __uint_as_float((unsigned int)u << 16);
}

// ---- prep: b0 = dtype detect; b1 = MFMA weight packs; rest = x->bf16 --------
__global__ __launch_bounds__(256) void prep(
    const unsigned* __restrict__ raw, int* __restrict__ flag, int E,
    const float* __restrict__ Wrel1, const float* __restrict__ Wroot1,
    const float* __restrict__ Wrel2, const float* __restrict__ Wroot2,
    unsigned short* __restrict__ Wp1rel, unsigned short* __restrict__ Wp1root,
    unsigned short* __restrict__ Wp2,
    const float* __restrict__ x, unsigned short* __restrict__ xb, long long n4)
{
    if (blockIdx.x == 0) {
        __shared__ unsigned red[256];
        unsigned v = 0;
        int lim = (E < 4096) ? E : 4096;
        for (int i = threadIdx.x; i < lim; i += 256) v |= raw[2 * i + 1];
        red[threadIdx.x] = v;
        __syncthreads();
        for (int s = 128; s > 0; s >>= 1) {
            if (threadIdx.x < s) red[threadIdx.x] |= red[threadIdx.x + s];
            __syncthreads();
        }
        if (threadIdx.x == 0) *flag = (red[0] == 0) ? 1 : 0;
    } else if (blockIdx.x == 1) {
        for (int i = threadIdx.x; i < 4096; i += 256) {
            int b = i & 7, l = (i >> 3) & 63, nt = (i >> 9) & 3, kc = i >> 11;
            int j = nt * 16 + (l & 15);
            int k = kc * 32 + ((l >> 4) << 3) + b;
            Wp1rel[i]  = f2bf(Wrel1[j * 64 + k]);
            Wp1root[i] = f2bf(Wroot1[j * 64 + k]);
            Wp2[i]     = f2bf((j < 32) ? Wrel2[j * 64 + k]
                                       : Wroot2[(j - 32) * 64 + k]);
        }
    } else {
        long long i = (long long)(blockIdx.x - 2) * 256 + threadIdx.x;
        long long stride = (long long)(gridDim.x - 2) * 256;
        for (; i < n4; i += stride) {
            float4 v = *(const float4*)(x + i * 4);
            ushort4 o;
            o.x = f2bf(v.x); o.y = f2bf(v.y); o.z = f2bf(v.z); o.w = f2bf(v.w);
            *(ushort4*)(xb + i * 4) = o;
        }
    }
}

// ---- p1: per-block coarse histogram into hb[c*B1 + blk] --------------------
__global__ __launch_bounds__(1024) void p1_hist(const void* __restrict__ raw,
                                                const int* __restrict__ flag,
                                                int* __restrict__ hb,
                                                int E, int C, int B1) {
    __shared__ int cnt[CMAX];
    int t = threadIdx.x;
    for (int i = t; i < C; i += 1024) cnt[i] = 0;
    __syncthreads();
    int fl = *flag;
    int ebase = blockIdx.x * 4096;
#pragma unroll
    for (int j = 0; j < 4; ++j) {
        int e = ebase + j * 1024 + t;
        if (e < E) {
            int d = fl ? (int)((const long long*)raw)[E + e] : ((const int*)raw)[E + e];
            atomicAdd(&cnt[d >> CSHIFT], 1);
        }
    }
    __syncthreads();
    for (int i = t; i < C; i += 1024) hb[i * B1 + blockIdx.x] = cnt[i];
}

// ---- flat exclusive scan over M elements (2 kernels; k3 folded into users) --
__global__ __launch_bounds__(1024) void scan_k1(const int* __restrict__ in,
                                                int* __restrict__ out,
                                                int* __restrict__ bsums, int M) {
    __shared__ int tmp[1024];
    int tid = threadIdx.x;
    int i = blockIdx.x * 1024 + tid;
    int v = (i < M) ? in[i] : 0;
    tmp[tid] = v;
    __syncthreads();
    for (int off = 1; off < 1024; off <<= 1) {
        int t = (tid >= off) ? tmp[tid - off] : 0;
        __syncthreads();
        tmp[tid] += t;
        __syncthreads();
    }
    if (i < M) out[i] = tmp[tid] - v;
    if (tid == 1023) bsums[blockIdx.x] = tmp[tid];
}

__global__ __launch_bounds__(1024) void scan_k2(int* __restrict__ bsums, int nb) {
    __shared__ int tmp[1024];
    int tid = threadIdx.x;
    int v = (tid < nb) ? bsums[tid] : 0;
    tmp[tid] = v;
    __syncthreads();
    for (int off = 1; off < 1024; off <<= 1) {
        int t = (tid >= off) ? tmp[tid - off] : 0;
        __syncthreads();
        tmp[tid] += t;
        __syncthreads();
    }
    if (tid < nb) bsums[tid] = tmp[tid] - v;
}

// ---- p3: scatter edges to bucket-partitioned part[] (LDS returning atomics) -
__global__ __launch_bounds__(1024) void p3_scatter(const void* __restrict__ raw,
                                                   const int* __restrict__ flag,
                                                   const float* __restrict__ ea,
                                                   const int* __restrict__ off,
                                                   const int* __restrict__ bsums,
                                                   long long* __restrict__ part,
                                                   int E, int C, int B1) {
    __shared__ int lcur[CMAX];
    int t = threadIdx.x;
    for (int i = t; i < C; i += 1024) {
        int idx = i * B1 + blockIdx.x;
        lcur[i] = off[idx] + bsums[idx >> 10];
    }
    __syncthreads();
    int fl = *flag;
    int ebase = blockIdx.x * 4096;
#pragma unroll
    for (int j = 0; j < 4; ++j) {
        int e = ebase + j * 1024 + t;
        if (e < E) {
            int s, d;
            if (fl) { const long long* p = (const long long*)raw; s = (int)p[e]; d = (int)p[E + e]; }
            else    { const int* p = (const int*)raw; s = p[e]; d = p[E + e]; }
            float w = ea[e];
            int slot = atomicAdd(&lcur[d >> CSHIFT], 1);
            long long pk = (unsigned int)(s | ((d & CMASK) << 20))
                         | ((long long)__float_as_int(w) << 32);
            part[slot] = pk;
        }
    }
}

// ---- p4: per-bucket exact grouping; writes deg, base, csr -------------------
__global__ __launch_bounds__(256) void p4_build(const int* __restrict__ off,
                                                const int* __restrict__ bsums,
                                                const long long* __restrict__ part,
                                                int2* __restrict__ csr,
                                                int* __restrict__ deg,
                                                int* __restrict__ base,
                                                int E, int N, int C, int B1) {
    __shared__ int ldeg[64], tmp[64], lcur[64];
    int c = blockIdx.x, t = threadIdx.x;
    int i0 = c * B1;
    int bstart = off[i0] + bsums[i0 >> 10];
    int bend;
    if (c + 1 < C) {
        int i1 = (c + 1) * B1;
        bend = off[i1] + bsums[i1 >> 10];
    } else {
        bend = E;
    }
    if (t < 64) ldeg[t] = 0;
    __syncthreads();
    for (int i = bstart + t; i < bend; i += 256) {
        int lo = (int)part[i];
        atomicAdd(&ldeg[(lo >> 20) & CMASK], 1);
    }
    __syncthreads();
    if (t < 64) tmp[t] = ldeg[t];
    __syncthreads();
    for (int o = 1; o < 64; o <<= 1) {
        int v = (t < 64 && t >= o) ? tmp[t - o] : 0;
        __syncthreads();
        if (t < 64) tmp[t] += v;
        __syncthreads();
    }
    if (t < 64) {
        int ex = tmp[t] - ldeg[t];
        lcur[t] = ex;
        int n = (c << CSHIFT) + t;
        if (n < N) { deg[n] = ldeg[t]; base[n] = bstart + ex; }
    }
    __syncthreads();
    for (int i = bstart + t; i < bend; i += 256) {
        long long pk = part[i];
        int lo = (int)pk;
        int r = atomicAdd(&lcur[(lo >> 20) & CMASK], 1);
        csr[bstart + r] = make_int2(lo & 0xFFFFF, (int)(pk >> 32));
    }
}

// ---- gather1: aggb[n] = bf16((sum_e w*xb[src])/max(deg,1)) ------------------
__global__ __launch_bounds__(256) void gather1(
    const unsigned short* __restrict__ xb, const int2* __restrict__ csr,
    const int* __restrict__ base, const int* __restrict__ deg,
    unsigned short* __restrict__ aggb, int N)
{
    int lane = threadIdx.x & 63;
    int wid = blockIdx.x * 4 + (threadIdx.x >> 6);
    int stride = gridDim.x * 4;
    for (int n = wid; n < N; n += stride) {
        int b = __builtin_amdgcn_readfirstlane(base[n]);
        int dg = __builtin_amdgcn_readfirstlane(deg[n]);
        float acc0 = 0.f, acc1 = 0.f, acc2 = 0.f, acc3 = 0.f;
        int i = b, e = b + dg;
        for (; i + 8 <= e; i += 8) {
            int2 r0 = csr[i], r1 = csr[i + 1], r2 = csr[i + 2], r3 = csr[i + 3];
            int2 r4 = csr[i + 4], r5 = csr[i + 5], r6 = csr[i + 6], r7 = csr[i + 7];
            float v0 = bf2f(xb[(size_t)r0.x * 64 + lane]);
            float v1 = bf2f(xb[(size_t)r1.x * 64 + lane]);
            float v2 = bf2f(xb[(size_t)r2.x * 64 + lane]);
            float v3 = bf2f(xb[(size_t)r3.x * 64 + lane]);
            float v4 = bf2f(xb[(size_t)r4.x * 64 + lane]);
            float v5 = bf2f(xb[(size_t)r5.x * 64 + lane]);
            float v6 = bf2f(xb[(size_t)r6.x * 64 + lane]);
            float v7 = bf2f(xb[(size_t)r7.x * 64 + lane]);
            acc0 = fmaf(__int_as_float(r0.y), v0, acc0);
            acc1 = fmaf(__int_as_float(r1.y), v1, acc1);
            acc2 = fmaf(__int_as_float(r2.y), v2, acc2);
            acc3 = fmaf(__int_as_float(r3.y), v3, acc3);
            acc0 = fmaf(__int_as_float(r4.y), v4, acc0);
            acc1 = fmaf(__int_as_float(r5.y), v5, acc1);
            acc2 = fmaf(__int_as_float(r6.y), v6, acc2);
            acc3 = fmaf(__int_as_float(r7.y), v7, acc3);
        }
        for (; i + 4 <= e; i += 4) {
            int2 r0 = csr[i], r1 = csr[i + 1], r2 = csr[i + 2], r3 = csr[i + 3];
            acc0 = fmaf(__int_as_float(r0.y), bf2f(xb[(size_t)r0.x * 64 + lane]), acc0);
            acc1 = fmaf(__int_as_float(r1.y), bf2f(xb[(size_t)r1.x * 64 + lane]), acc1);
            acc2 = fmaf(__int_as_float(r2.y), bf2f(xb[(size_t)r2.x * 64 + lane]), acc2);
            acc3 = fmaf(__int_as_float(r3.y), bf2f(xb[(size_t)r3.x * 64 + lane]), acc3);
        }
        for (; i < e; ++i) {
            int2 r = csr[i];
            acc0 = fmaf(__int_as_float(r.y), bf2f(xb[(size_t)r.x * 64 + lane]), acc0);
        }
        float inv = 1.0f / fmaxf((float)dg, 1.0f);
        aggb[(size_t)n * 64 + lane] = f2bf(((acc0 + acc1) + (acc2 + acc3)) * inv);
    }
}

// ---- node_mfma: h = sig(agg@W1rel^T + b1 + x@W1root^T); [hr|hro]=h@W2^T -----
__global__ __launch_bounds__(256) void node_mfma(
    const unsigned short* __restrict__ aggb, const unsigned short* __restrict__ xb,
    const unsigned short* __restrict__ Wp1rel, const unsigned short* __restrict__ Wp1root,
    const unsigned short* __restrict__ Wp2,
    const float* __restrict__ brel1, const float* __restrict__ brel2,
    unsigned short* __restrict__ hrb, float* __restrict__ hro, int N)
{
    __shared__ unsigned short hx[64 * 72];
    int t = threadIdx.x;
    int lane = t & 63;
    int w = t >> 6;
    int col = lane & 15;
    int kg = lane >> 4;
    int n0 = blockIdx.x * 64;
    int rowA = n0 + w * 16 + col;
    size_t rowAc = (size_t)((rowA < N) ? rowA : (N - 1)) * 64;

    const bf16x8* B1r = (const bf16x8*)Wp1rel;
    const bf16x8* B1o = (const bf16x8*)Wp1root;
    const bf16x8* B2  = (const bf16x8*)Wp2;

    f32x4 acc0, acc1, acc2, acc3;
    {
        float b0 = brel1[col], b1 = brel1[16 + col];
        float b2 = brel1[32 + col], b3 = brel1[48 + col];
        acc0 = (f32x4){b0, b0, b0, b0};
        acc1 = (f32x4){b1, b1, b1, b1};
        acc2 = (f32x4){b2, b2, b2, b2};
        acc3 = (f32x4){b3, b3, b3, b3};
    }

#define MFMA __builtin_amdgcn_mfma_f32_16x16x32_bf16
#pragma unroll
    for (int kc = 0; kc < 2; ++kc) {
        bf16x8 a = *(const bf16x8*)(aggb + rowAc + kc * 32 + kg * 8);
        acc0 = MFMA(a, B1r[(kc * 4 + 0) * 64 + lane], acc0, 0, 0, 0);
        acc1 = MFMA(a, B1r[(kc * 4 + 1) * 64 + lane], acc1, 0, 0, 0);
        acc2 = MFMA(a, B1r[(kc * 4 + 2) * 64 + lane], acc2, 0, 0, 0);
        acc3 = MFMA(a, B1r[(kc * 4 + 3) * 64 + lane], acc3, 0, 0, 0);
    }
#pragma unroll
    for (int kc = 0; kc < 2; ++kc) {
        bf16x8 a = *(const bf16x8*)(xb + rowAc + kc * 32 + kg * 8);
        acc0 = MFMA(a, B1o[(kc * 4 + 0) * 64 + lane], acc0, 0, 0, 0);
        acc1 = MFMA(a, B1o[(kc * 4 + 1) * 64 + lane], acc1, 0, 0, 0);
        acc2 = MFMA(a, B1o[(kc * 4 + 2) * 64 + lane], acc2, 0, 0, 0);
        acc3 = MFMA(a, B1o[(kc * 4 + 3) * 64 + lane], acc3, 0, 0, 0);
    }

#define SIG4(A) \
    A[0] = 1.f / (1.f + __expf(-A[0])); A[1] = 1.f / (1.f + __expf(-A[1])); \
    A[2] = 1.f / (1.f + __expf(-A[2])); A[3] = 1.f / (1.f + __expf(-A[3]));
    SIG4(acc0) SIG4(acc1) SIG4(acc2) SIG4(acc3)
#undef SIG4

    {
        int rbase = (w * 16 + 4 * kg) * 72;
#define STORE_H(V)                                                       \
        hx[rbase + (V) * 72 + col]      = f2bf(acc0[V]);                 \
        hx[rbase + (V) * 72 + 16 + col] = f2bf(acc1[V]);                 \
        hx[rbase + (V) * 72 + 32 + col] = f2bf(acc2[V]);                 \
        hx[rbase + (V) * 72 + 48 + col] = f2bf(acc3[V]);
        STORE_H(0) STORE_H(1) STORE_H(2) STORE_H(3)
#undef STORE_H
    }
    __syncthreads();

    acc0 = (f32x4){0.f, 0.f, 0.f, 0.f};
    acc1 = (f32x4){0.f, 0.f, 0.f, 0.f};
    {
        float b2a = brel2[col], b2b = brel2[16 + col];
        acc2 = (f32x4){b2a, b2a, b2a, b2a};
        acc3 = (f32x4){b2b, b2b, b2b, b2b};
    }
#pragma unroll
    for (int kc = 0; kc < 2; ++kc) {
        bf16x8 a = *(const bf16x8*)(&hx[(w * 16 + col) * 72 + kc * 32 + kg * 8]);
        acc0 = MFMA(a, B2[(kc * 4 + 0) * 64 + lane], acc0, 0, 0, 0);
        acc1 = MFMA(a, B2[(kc * 4 + 1) * 64 + lane], acc1, 0, 0, 0);
        acc2 = MFMA(a, B2[(kc * 4 + 2) * 64 + lane], acc2, 0, 0, 0);
        acc3 = MFMA(a, B2[(kc * 4 + 3) * 64 + lane], acc3, 0, 0, 0);
    }
#undef MFMA

    {
        int nbase = n0 + w * 16 + 4 * kg;
#define STORE_OUT(V)                                                        \
        if (nbase + (V) < N) {                                              \
            size_t r32 = (size_t)(nbase + (V)) * 32;                        \
            hrb[r32 + col]      = f2bf(acc0[V]);                            \
            hrb[r32 + 16 + col] = f2bf(acc1[V]);                            \
            hro[r32 + col]      = acc2[V];                                  \
            hro[r32 + 16 + col] = acc3[V];                                  \
        }
        STORE_OUT(0) STORE_OUT(1) STORE_OUT(2) STORE_OUT(3)
#undef STORE_OUT
    }
}

// ---- gather2 v4: wave = 4 nodes x 16 lanes, packed uint hrb loads -----------
__global__ __launch_bounds__(256) void gather2(
    const unsigned short* __restrict__ hrb, const float* __restrict__ hro,
    const int2* __restrict__ csr, const int* __restrict__ base,
    const int* __restrict__ deg, float* __restrict__ out, int N)
{
    int lane = threadIdx.x & 63;
    int q = lane >> 4;
    int fl = lane & 15;
    int wid = blockIdx.x * 4 + (threadIdx.x >> 6);
    int stride = gridDim.x * 4;
    for (int g = wid * 4; g < N; g += stride * 4) {
        int n = g + q;
        bool valid = n < N;
        int nc = valid ? n : (N - 1);
        int b = base[nc];
        int dg = deg[nc];
        float a0 = 0.f, a1 = 0.f, a2 = 0.f, a3 = 0.f;
        float b0 = 0.f, b1 = 0.f, b2 = 0.f, b3 = 0.f;
        int i = b, e = b + dg;
        for (; i + 4 <= e; i += 4) {
            int2 r0 = csr[i], r1 = csr[i + 1], r2 = csr[i + 2], r3 = csr[i + 3];
            unsigned u0 = *(const unsigned*)(hrb + (size_t)r0.x * 32 + fl * 2);
            unsigned u1 = *(const unsigned*)(hrb + (size_t)r1.x * 32 + fl * 2);
            unsigned u2 = *(const unsigned*)(hrb + (size_t)r2.x * 32 + fl * 2);
            unsigned u3 = *(const unsigned*)(hrb + (size_t)r3.x * 32 + fl * 2);
            float w0 = __int_as_float(r0.y), w1 = __int_as_float(r1.y);
            float w2 = __int_as_float(r2.y), w3 = __int_as_float(r3.y);
            a0 = fmaf(w0, __uint_as_float(u0 << 16), a0);
            b0 = fmaf(w0, __uint_as_float(u0 & 0xffff0000u), b0);
            a1 = fmaf(w1, __uint_as_float(u1 << 16), a1);
            b1 = fmaf(w1, __uint_as_float(u1 & 0xffff0000u), b1);
            a2 = fmaf(w2, __uint_as_float(u2 << 16), a2);
            b2 = fmaf(w2, __uint_as_float(u2 & 0xffff0000u), b2);
            a3 = fmaf(w3, __uint_as_float(u3 << 16), a3);
            b3 = fmaf(w3, __uint_as_float(u3 & 0xffff0000u), b3);
        }
        for (; i < e; ++i) {
            int2 r = csr[i];
            unsigned u = *(const unsigned*)(hrb + (size_t)r.x * 32 + fl * 2);
            float w = __int_as_float(r.y);
            a0 = fmaf(w, __uint_as_float(u << 16), a0);
            b0 = fmaf(w, __uint_as_float(u & 0xffff0000u), b0);
        }
        if (valid) {
            float inv = 1.0f / fmaxf((float)dg, 1.0f);
            float s0 = ((a0 + a1) + (a2 + a3)) * inv;
            float s1 = ((b0 + b1) + (b2 + b3)) * inv;
            const float* hsrc = hro + (size_t)n * 32 + fl * 2;
            float2 hv = *(const float2*)hsrc;
            *(float2*)(out + (size_t)n * 32 + fl * 2) =
                make_float2(s0 + hv.x, s1 + hv.y);
        }
    }
}

extern "C" void kernel_launch(void* const* d_in, const int* in_sizes, int n_in,
                              void* d_out, int out_size, void* d_ws, size_t ws_size,
                              hipStream_t stream) {
    const float* x      = (const float*)d_in[0];
    const void*  ei_raw = d_in[1];
    const float* ea     = (const float*)d_in[2];
    const float* Wrel1  = (const float*)d_in[3];
    const float* brel1  = (const float*)d_in[4];
    const float* Wroot1 = (const float*)d_in[5];
    const float* Wrel2  = (const float*)d_in[6];
    const float* brel2  = (const float*)d_in[7];
    const float* Wroot2 = (const float*)d_in[8];
    float* out = (float*)d_out;

    const int N = in_sizes[0] / NF;          // 100000
    const int E = in_sizes[2];               // 1000000
    const int C  = (N + CMASK) >> CSHIFT;    // 1563 coarse buckets
    const int B1 = (E + 4095) / 4096;        // 245 edge blocks
    const int M  = C * B1;                   // ~383k
    const int nbM = (M + 1023) / 1024;       // ~374

    // workspace layout
    long long* part = (long long*)d_ws;                 // E (8 MB)
    int2*  csr     = (int2*)(part + E);                 // E (8 MB); hb overlaps pre-p4
    int*   off     = (int*)(csr + E);                   // M
    int*   bsums   = off + M;                           // nbM (+pad to 1024)
    int*   flag    = bsums + 1024;                      // 1 (+3 pad)
    int*   deg     = flag + 4;                          // N
    int*   base    = deg + N;                           // N
    float* hro     = (float*)(base + N);                // N*32 fp32
    unsigned short* xb     = (unsigned short*)(hro + (size_t)N * 32); // N*64 bf16
    unsigned short* aggb   = xb + (size_t)N * 64;                     // N*64 bf16
    unsigned short* hrb    = aggb + (size_t)N * 64;                   // N*32 bf16
    unsigned short* Wp1rel = hrb + (size_t)N * 32;                    // 4096
    unsigned short* Wp1root= Wp1rel + 4096;                           // 4096
    unsigned short* Wp2    = Wp1root + 4096;                          // 4096

    // hb stored in csr buffer (dead until p4 writes it)
    prep<<<2048, 256, 0, stream>>>((const unsigned*)ei_raw, flag, E,
                                   Wrel1, Wroot1, Wrel2, Wroot2,
                                   Wp1rel, Wp1root, Wp2, x, xb, (long long)N * 16);
    p1_hist<<<B1, 1024, 0, stream>>>(ei_raw, flag, (int*)csr, E, C, B1);
    scan_k1<<<nbM, 1024, 0, stream>>>((int*)csr, off, bsums, M);
    scan_k2<<<1, 1024, 0, stream>>>(bsums, nbM);
    p3_scatter<<<B1, 1024, 0, stream>>>(ei_raw, flag, ea, off, bsums, part, E, C, B1);
    p4_build<<<C, 256, 0, stream>>>(off, bsums, part, csr, deg, base, E, N, C, B1);

    gather1<<<2048, 256, 0, stream>>>(xb, csr, base, deg, aggb, N);
    node_mfma<<<(N + 63) / 64, 256, 0, stream>>>(aggb, xb, Wp1rel, Wp1root, Wp2,
                                                 brel1, brel2, hrb, hro, N);
    gather2<<<2048, 256, 0, stream>>>(hrb, hro, csr, base, deg, out, N);
}

// Round 22
// 122.561 us; speedup vs baseline: 1.0344x; 1.0344x over previous
//
#include <hip/hip_runtime.h>
#include <hip/hip_bf16.h>

// GraphConv x2 via dst-sorted CSR gather.
// CSR build with ZERO global returning atomics (LDS-atomic 4-phase).
// R22: CSHIFT back to 7 (R21 post-mortem: CSHIFT=6 doubled M -> p1/scan/p3
// costs grew more than p4 gained); keep scan_k3 folded into p3/p4.
// node_mfma: node transform on matrix cores. gather2 v4: 4 nodes x 16 lanes.

#define NF 64
#define CSHIFT 7
#define CMASK 127
#define CMAX 1024   // supports N <= 131072

typedef __attribute__((ext_vector_type(8))) short bf16x8;
typedef __attribute__((ext_vector_type(4))) float f32x4;

__device__ __forceinline__ unsigned short f2bf(float f) {
    __hip_bfloat16 h = __float2bfloat16(f);
    return *reinterpret_cast<unsigned short*>(&h);
}
__device__ __forceinline__ float bf2f(unsigned short u) {
    return __uint_as_float((unsigned int)u << 16);
}

// ---- prep: b0 = dtype detect; b1 = MFMA weight packs; rest = x->bf16 --------
__global__ __launch_bounds__(256) void prep(
    const unsigned* __restrict__ raw, int* __restrict__ flag, int E,
    const float* __restrict__ Wrel1, const float* __restrict__ Wroot1,
    const float* __restrict__ Wrel2, const float* __restrict__ Wroot2,
    unsigned short* __restrict__ Wp1rel, unsigned short* __restrict__ Wp1root,
    unsigned short* __restrict__ Wp2,
    const float* __restrict__ x, unsigned short* __restrict__ xb, long long n4)
{
    if (blockIdx.x == 0) {
        __shared__ unsigned red[256];
        unsigned v = 0;
        int lim = (E < 4096) ? E : 4096;
        for (int i = threadIdx.x; i < lim; i += 256) v |= raw[2 * i + 1];
        red[threadIdx.x] = v;
        __syncthreads();
        for (int s = 128; s > 0; s >>= 1) {
            if (threadIdx.x < s) red[threadIdx.x] |= red[threadIdx.x + s];
            __syncthreads();
        }
        if (threadIdx.x == 0) *flag = (red[0] == 0) ? 1 : 0;
    } else if (blockIdx.x == 1) {
        for (int i = threadIdx.x; i < 4096; i += 256) {
            int b = i & 7, l = (i >> 3) & 63, nt = (i >> 9) & 3, kc = i >> 11;
            int j = nt * 16 + (l & 15);
            int k = kc * 32 + ((l >> 4) << 3) + b;
            Wp1rel[i]  = f2bf(Wrel1[j * 64 + k]);
            Wp1root[i] = f2bf(Wroot1[j * 64 + k]);
            Wp2[i]     = f2bf((j < 32) ? Wrel2[j * 64 + k]
                                       : Wroot2[(j - 32) * 64 + k]);
        }
    } else {
        long long i = (long long)(blockIdx.x - 2) * 256 + threadIdx.x;
        long long stride = (long long)(gridDim.x - 2) * 256;
        for (; i < n4; i += stride) {
            float4 v = *(const float4*)(x + i * 4);
            ushort4 o;
            o.x = f2bf(v.x); o.y = f2bf(v.y); o.z = f2bf(v.z); o.w = f2bf(v.w);
            *(ushort4*)(xb + i * 4) = o;
        }
    }
}

// ---- p1: per-block coarse histogram into hb[c*B1 + blk] --------------------
__global__ __launch_bounds__(1024) void p1_hist(const void* __restrict__ raw,
                                                const int* __restrict__ flag,
                                                int* __restrict__ hb,
                                                int E, int C, int B1) {
    __shared__ int cnt[CMAX];
    int t = threadIdx.x;
    for (int i = t; i < C; i += 1024) cnt[i] = 0;
    __syncthreads();
    int fl = *flag;
    int ebase = blockIdx.x * 4096;
#pragma unroll
    for (int j = 0; j < 4; ++j) {
        int e = ebase + j * 1024 + t;
        if (e < E) {
            int d = fl ? (int)((const long long*)raw)[E + e] : ((const int*)raw)[E + e];
            atomicAdd(&cnt[d >> CSHIFT], 1);
        }
    }
    __syncthreads();
    for (int i = t; i < C; i += 1024) hb[i * B1 + blockIdx.x] = cnt[i];
}

// ---- flat exclusive scan over M elements (2 kernels; k3 folded into users) --
__global__ __launch_bounds__(1024) void scan_k1(const int* __restrict__ in,
                                                int* __restrict__ out,
                                                int* __restrict__ bsums, int M) {
    __shared__ int tmp[1024];
    int tid = threadIdx.x;
    int i = blockIdx.x * 1024 + tid;
    int v = (i < M) ? in[i] : 0;
    tmp[tid] = v;
    __syncthreads();
    for (int off = 1; off < 1024; off <<= 1) {
        int t = (tid >= off) ? tmp[tid - off] : 0;
        __syncthreads();
        tmp[tid] += t;
        __syncthreads();
    }
    if (i < M) out[i] = tmp[tid] - v;
    if (tid == 1023) bsums[blockIdx.x] = tmp[tid];
}

__global__ __launch_bounds__(1024) void scan_k2(int* __restrict__ bsums, int nb) {
    __shared__ int tmp[1024];
    int tid = threadIdx.x;
    int v = (tid < nb) ? bsums[tid] : 0;
    tmp[tid] = v;
    __syncthreads();
    for (int off = 1; off < 1024; off <<= 1) {
        int t = (tid >= off) ? tmp[tid - off] : 0;
        __syncthreads();
        tmp[tid] += t;
        __syncthreads();
    }
    if (tid < nb) bsums[tid] = tmp[tid] - v;
}

// ---- p3: scatter edges to bucket-partitioned part[] (LDS returning atomics) -
__global__ __launch_bounds__(1024) void p3_scatter(const void* __restrict__ raw,
                                                   const int* __restrict__ flag,
                                                   const float* __restrict__ ea,
                                                   const int* __restrict__ off,
                                                   const int* __restrict__ bsums,
                                                   long long* __restrict__ part,
                                                   int E, int C, int B1) {
    __shared__ int lcur[CMAX];
    int t = threadIdx.x;
    for (int i = t; i < C; i += 1024) {
        int idx = i * B1 + blockIdx.x;
        lcur[i] = off[idx] + bsums[idx >> 10];
    }
    __syncthreads();
    int fl = *flag;
    int ebase = blockIdx.x * 4096;
#pragma unroll
    for (int j = 0; j < 4; ++j) {
        int e = ebase + j * 1024 + t;
        if (e < E) {
            int s, d;
            if (fl) { const long long* p = (const long long*)raw; s = (int)p[e]; d = (int)p[E + e]; }
            else    { const int* p = (const int*)raw; s = p[e]; d = p[E + e]; }
            float w = ea[e];
            int slot = atomicAdd(&lcur[d >> CSHIFT], 1);
            long long pk = (unsigned int)(s | ((d & CMASK) << 20))
                         | ((long long)__float_as_int(w) << 32);
            part[slot] = pk;
        }
    }
}

// ---- p4: per-bucket exact grouping; writes deg, base, csr -------------------
__global__ __launch_bounds__(256) void p4_build(const int* __restrict__ off,
                                                const int* __restrict__ bsums,
                                                const long long* __restrict__ part,
                                                int2* __restrict__ csr,
                                                int* __restrict__ deg,
                                                int* __restrict__ base,
                                                int E, int N, int C, int B1) {
    __shared__ int ldeg[128], tmp[128], lcur[128];
    int c = blockIdx.x, t = threadIdx.x;
    int i0 = c * B1;
    int bstart = off[i0] + bsums[i0 >> 10];
    int bend;
    if (c + 1 < C) {
        int i1 = (c + 1) * B1;
        bend = off[i1] + bsums[i1 >> 10];
    } else {
        bend = E;
    }
    if (t < 128) ldeg[t] = 0;
    __syncthreads();
    for (int i = bstart + t; i < bend; i += 256) {
        int lo = (int)part[i];
        atomicAdd(&ldeg[(lo >> 20) & CMASK], 1);
    }
    __syncthreads();
    if (t < 128) tmp[t] = ldeg[t];
    __syncthreads();
    for (int o = 1; o < 128; o <<= 1) {
        int v = (t < 128 && t >= o) ? tmp[t - o] : 0;
        __syncthreads();
        if (t < 128) tmp[t] += v;
        __syncthreads();
    }
    if (t < 128) {
        int ex = tmp[t] - ldeg[t];
        lcur[t] = ex;
        int n = (c << CSHIFT) + t;
        if (n < N) { deg[n] = ldeg[t]; base[n] = bstart + ex; }
    }
    __syncthreads();
    for (int i = bstart + t; i < bend; i += 256) {
        long long pk = part[i];
        int lo = (int)pk;
        int r = atomicAdd(&lcur[(lo >> 20) & CMASK], 1);
        csr[bstart + r] = make_int2(lo & 0xFFFFF, (int)(pk >> 32));
    }
}

// ---- gather1: aggb[n] = bf16((sum_e w*xb[src])/max(deg,1)) ------------------
__global__ __launch_bounds__(256) void gather1(
    const unsigned short* __restrict__ xb, const int2* __restrict__ csr,
    const int* __restrict__ base, const int* __restrict__ deg,
    unsigned short* __restrict__ aggb, int N)
{
    int lane = threadIdx.x & 63;
    int wid = blockIdx.x * 4 + (threadIdx.x >> 6);
    int stride = gridDim.x * 4;
    for (int n = wid; n < N; n += stride) {
        int b = __builtin_amdgcn_readfirstlane(base[n]);
        int dg = __builtin_amdgcn_readfirstlane(deg[n]);
        float acc0 = 0.f, acc1 = 0.f, acc2 = 0.f, acc3 = 0.f;
        int i = b, e = b + dg;
        for (; i + 8 <= e; i += 8) {
            int2 r0 = csr[i], r1 = csr[i + 1], r2 = csr[i + 2], r3 = csr[i + 3];
            int2 r4 = csr[i + 4], r5 = csr[i + 5], r6 = csr[i + 6], r7 = csr[i + 7];
            float v0 = bf2f(xb[(size_t)r0.x * 64 + lane]);
            float v1 = bf2f(xb[(size_t)r1.x * 64 + lane]);
            float v2 = bf2f(xb[(size_t)r2.x * 64 + lane]);
            float v3 = bf2f(xb[(size_t)r3.x * 64 + lane]);
            float v4 = bf2f(xb[(size_t)r4.x * 64 + lane]);
            float v5 = bf2f(xb[(size_t)r5.x * 64 + lane]);
            float v6 = bf2f(xb[(size_t)r6.x * 64 + lane]);
            float v7 = bf2f(xb[(size_t)r7.x * 64 + lane]);
            acc0 = fmaf(__int_as_float(r0.y), v0, acc0);
            acc1 = fmaf(__int_as_float(r1.y), v1, acc1);
            acc2 = fmaf(__int_as_float(r2.y), v2, acc2);
            acc3 = fmaf(__int_as_float(r3.y), v3, acc3);
            acc0 = fmaf(__int_as_float(r4.y), v4, acc0);
            acc1 = fmaf(__int_as_float(r5.y), v5, acc1);
            acc2 = fmaf(__int_as_float(r6.y), v6, acc2);
            acc3 = fmaf(__int_as_float(r7.y), v7, acc3);
        }
        for (; i + 4 <= e; i += 4) {
            int2 r0 = csr[i], r1 = csr[i + 1], r2 = csr[i + 2], r3 = csr[i + 3];
            acc0 = fmaf(__int_as_float(r0.y), bf2f(xb[(size_t)r0.x * 64 + lane]), acc0);
            acc1 = fmaf(__int_as_float(r1.y), bf2f(xb[(size_t)r1.x * 64 + lane]), acc1);
            acc2 = fmaf(__int_as_float(r2.y), bf2f(xb[(size_t)r2.x * 64 + lane]), acc2);
            acc3 = fmaf(__int_as_float(r3.y), bf2f(xb[(size_t)r3.x * 64 + lane]), acc3);
        }
        for (; i < e; ++i) {
            int2 r = csr[i];
            acc0 = fmaf(__int_as_float(r.y), bf2f(xb[(size_t)r.x * 64 + lane]), acc0);
        }
        float inv = 1.0f / fmaxf((float)dg, 1.0f);
        aggb[(size_t)n * 64 + lane] = f2bf(((acc0 + acc1) + (acc2 + acc3)) * inv);
    }
}

// ---- node_mfma: h = sig(agg@W1rel^T + b1 + x@W1root^T); [hr|hro]=h@W2^T -----
__global__ __launch_bounds__(256) void node_mfma(
    const unsigned short* __restrict__ aggb, const unsigned short* __restrict__ xb,
    const unsigned short* __restrict__ Wp1rel, const unsigned short* __restrict__ Wp1root,
    const unsigned short* __restrict__ Wp2,
    const float* __restrict__ brel1, const float* __restrict__ brel2,
    unsigned short* __restrict__ hrb, float* __restrict__ hro, int N)
{
    __shared__ unsigned short hx[64 * 72];
    int t = threadIdx.x;
    int lane = t & 63;
    int w = t >> 6;
    int col = lane & 15;
    int kg = lane >> 4;
    int n0 = blockIdx.x * 64;
    int rowA = n0 + w * 16 + col;
    size_t rowAc = (size_t)((rowA < N) ? rowA : (N - 1)) * 64;

    const bf16x8* B1r = (const bf16x8*)Wp1rel;
    const bf16x8* B1o = (const bf16x8*)Wp1root;
    const bf16x8* B2  = (const bf16x8*)Wp2;

    f32x4 acc0, acc1, acc2, acc3;
    {
        float b0 = brel1[col], b1 = brel1[16 + col];
        float b2 = brel1[32 + col], b3 = brel1[48 + col];
        acc0 = (f32x4){b0, b0, b0, b0};
        acc1 = (f32x4){b1, b1, b1, b1};
        acc2 = (f32x4){b2, b2, b2, b2};
        acc3 = (f32x4){b3, b3, b3, b3};
    }

#define MFMA __builtin_amdgcn_mfma_f32_16x16x32_bf16
#pragma unroll
    for (int kc = 0; kc < 2; ++kc) {
        bf16x8 a = *(const bf16x8*)(aggb + rowAc + kc * 32 + kg * 8);
        acc0 = MFMA(a, B1r[(kc * 4 + 0) * 64 + lane], acc0, 0, 0, 0);
        acc1 = MFMA(a, B1r[(kc * 4 + 1) * 64 + lane], acc1, 0, 0, 0);
        acc2 = MFMA(a, B1r[(kc * 4 + 2) * 64 + lane], acc2, 0, 0, 0);
        acc3 = MFMA(a, B1r[(kc * 4 + 3) * 64 + lane], acc3, 0, 0, 0);
    }
#pragma unroll
    for (int kc = 0; kc < 2; ++kc) {
        bf16x8 a = *(const bf16x8*)(xb + rowAc + kc * 32 + kg * 8);
        acc0 = MFMA(a, B1o[(kc * 4 + 0) * 64 + lane], acc0, 0, 0, 0);
        acc1 = MFMA(a, B1o[(kc * 4 + 1) * 64 + lane], acc1, 0, 0, 0);
        acc2 = MFMA(a, B1o[(kc * 4 + 2) * 64 + lane], acc2, 0, 0, 0);
        acc3 = MFMA(a, B1o[(kc * 4 + 3) * 64 + lane], acc3, 0, 0, 0);
    }

#define SIG4(A) \
    A[0] = 1.f / (1.f + __expf(-A[0])); A[1] = 1.f / (1.f + __expf(-A[1])); \
    A[2] = 1.f / (1.f + __expf(-A[2])); A[3] = 1.f / (1.f + __expf(-A[3]));
    SIG4(acc0) SIG4(acc1) SIG4(acc2) SIG4(acc3)
#undef SIG4

    {
        int rbase = (w * 16 + 4 * kg) * 72;
#define STORE_H(V)                                                       \
        hx[rbase + (V) * 72 + col]      = f2bf(acc0[V]);                 \
        hx[rbase + (V) * 72 + 16 + col] = f2bf(acc1[V]);                 \
        hx[rbase + (V) * 72 + 32 + col] = f2bf(acc2[V]);                 \
        hx[rbase + (V) * 72 + 48 + col] = f2bf(acc3[V]);
        STORE_H(0) STORE_H(1) STORE_H(2) STORE_H(3)
#undef STORE_H
    }
    __syncthreads();

    acc0 = (f32x4){0.f, 0.f, 0.f, 0.f};
    acc1 = (f32x4){0.f, 0.f, 0.f, 0.f};
    {
        float b2a = brel2[col], b2b = brel2[16 + col];
        acc2 = (f32x4){b2a, b2a, b2a, b2a};
        acc3 = (f32x4){b2b, b2b, b2b, b2b};
    }
#pragma unroll
    for (int kc = 0; kc < 2; ++kc) {
        bf16x8 a = *(const bf16x8*)(&hx[(w * 16 + col) * 72 + kc * 32 + kg * 8]);
        acc0 = MFMA(a, B2[(kc * 4 + 0) * 64 + lane], acc0, 0, 0, 0);
        acc1 = MFMA(a, B2[(kc * 4 + 1) * 64 + lane], acc1, 0, 0, 0);
        acc2 = MFMA(a, B2[(kc * 4 + 2) * 64 + lane], acc2, 0, 0, 0);
        acc3 = MFMA(a, B2[(kc * 4 + 3) * 64 + lane], acc3, 0, 0, 0);
    }
#undef MFMA

    {
        int nbase = n0 + w * 16 + 4 * kg;
#define STORE_OUT(V)                                                        \
        if (nbase + (V) < N) {                                              \
            size_t r32 = (size_t)(nbase + (V)) * 32;                        \
            hrb[r32 + col]      = f2bf(acc0[V]);                            \
            hrb[r32 + 16 + col] = f2bf(acc1[V]);                            \
            hro[r32 + col]      = acc2[V];                                  \
            hro[r32 + 16 + col] = acc3[V];                                  \
        }
        STORE_OUT(0) STORE_OUT(1) STORE_OUT(2) STORE_OUT(3)
#undef STORE_OUT
    }
}

// ---- gather2 v4: wave = 4 nodes x 16 lanes, packed uint hrb loads -----------
__global__ __launch_bounds__(256) void gather2(
    const unsigned short* __restrict__ hrb, const float* __restrict__ hro,
    const int2* __restrict__ csr, const int* __restrict__ base,
    const int* __restrict__ deg, float* __restrict__ out, int N)
{
    int lane = threadIdx.x & 63;
    int q = lane >> 4;
    int fl = lane & 15;
    int wid = blockIdx.x * 4 + (threadIdx.x >> 6);
    int stride = gridDim.x * 4;
    for (int g = wid * 4; g < N; g += stride * 4) {
        int n = g + q;
        bool valid = n < N;
        int nc = valid ? n : (N - 1);
        int b = base[nc];
        int dg = deg[nc];
        float a0 = 0.f, a1 = 0.f, a2 = 0.f, a3 = 0.f;
        float b0 = 0.f, b1 = 0.f, b2 = 0.f, b3 = 0.f;
        int i = b, e = b + dg;
        for (; i + 4 <= e; i += 4) {
            int2 r0 = csr[i], r1 = csr[i + 1], r2 = csr[i + 2], r3 = csr[i + 3];
            unsigned u0 = *(const unsigned*)(hrb + (size_t)r0.x * 32 + fl * 2);
            unsigned u1 = *(const unsigned*)(hrb + (size_t)r1.x * 32 + fl * 2);
            unsigned u2 = *(const unsigned*)(hrb + (size_t)r2.x * 32 + fl * 2);
            unsigned u3 = *(const unsigned*)(hrb + (size_t)r3.x * 32 + fl * 2);
            float w0 = __int_as_float(r0.y), w1 = __int_as_float(r1.y);
            float w2 = __int_as_float(r2.y), w3 = __int_as_float(r3.y);
            a0 = fmaf(w0, __uint_as_float(u0 << 16), a0);
            b0 = fmaf(w0, __uint_as_float(u0 & 0xffff0000u), b0);
            a1 = fmaf(w1, __uint_as_float(u1 << 16), a1);
            b1 = fmaf(w1, __uint_as_float(u1 & 0xffff0000u), b1);
            a2 = fmaf(w2, __uint_as_float(u2 << 16), a2);
            b2 = fmaf(w2, __uint_as_float(u2 & 0xffff0000u), b2);
            a3 = fmaf(w3, __uint_as_float(u3 << 16), a3);
            b3 = fmaf(w3, __uint_as_float(u3 & 0xffff0000u), b3);
        }
        for (; i < e; ++i) {
            int2 r = csr[i];
            unsigned u = *(const unsigned*)(hrb + (size_t)r.x * 32 + fl * 2);
            float w = __int_as_float(r.y);
            a0 = fmaf(w, __uint_as_float(u << 16), a0);
            b0 = fmaf(w, __uint_as_float(u & 0xffff0000u), b0);
        }
        if (valid) {
            float inv = 1.0f / fmaxf((float)dg, 1.0f);
            float s0 = ((a0 + a1) + (a2 + a3)) * inv;
            float s1 = ((b0 + b1) + (b2 + b3)) * inv;
            const float* hsrc = hro + (size_t)n * 32 + fl * 2;
            float2 hv = *(const float2*)hsrc;
            *(float2*)(out + (size_t)n * 32 + fl * 2) =
                make_float2(s0 + hv.x, s1 + hv.y);
        }
    }
}

extern "C" void kernel_launch(void* const* d_in, const int* in_sizes, int n_in,
                              void* d_out, int out_size, void* d_ws, size_t ws_size,
                              hipStream_t stream) {
    const float* x      = (const float*)d_in[0];
    const void*  ei_raw = d_in[1];
    const float* ea     = (const float*)d_in[2];
    const float* Wrel1  = (const float*)d_in[3];
    const float* brel1  = (const float*)d_in[4];
    const float* Wroot1 = (const float*)d_in[5];
    const float* Wrel2  = (const float*)d_in[6];
    const float* brel2  = (const float*)d_in[7];
    const float* Wroot2 = (const float*)d_in[8];
    float* out = (float*)d_out;

    const int N = in_sizes[0] / NF;          // 100000
    const int E = in_sizes[2];               // 1000000
    const int C  = (N + CMASK) >> CSHIFT;    // 782 coarse buckets
    const int B1 = (E + 4095) / 4096;        // 245 edge blocks
    const int M  = C * B1;                   // 191590
    const int nbM = (M + 1023) / 1024;       // 188

    // workspace layout
    long long* part = (long long*)d_ws;                 // E (8 MB)
    int2*  csr     = (int2*)(part + E);                 // E (8 MB); hb overlaps pre-p4
    int*   off     = (int*)(csr + E);                   // M
    int*   bsums   = off + M;                           // nbM (+pad to 1024)
    int*   flag    = bsums + 1024;                      // 1 (+3 pad)
    int*   deg     = flag + 4;                          // N
    int*   base    = deg + N;                           // N
    float* hro     = (float*)(base + N);                // N*32 fp32
    unsigned short* xb     = (unsigned short*)(hro + (size_t)N * 32); // N*64 bf16
    unsigned short* aggb   = xb + (size_t)N * 64;                     // N*64 bf16
    unsigned short* hrb    = aggb + (size_t)N * 64;                   // N*32 bf16
    unsigned short* Wp1rel = hrb + (size_t)N * 32;                    // 4096
    unsigned short* Wp1root= Wp1rel + 4096;                           // 4096
    unsigned short* Wp2    = Wp1root + 4096;                          // 4096

    // hb stored in csr buffer (dead until p4 writes it)
    prep<<<2048, 256, 0, stream>>>((const unsigned*)ei_raw, flag, E,
                                   Wrel1, Wroot1, Wrel2, Wroot2,
                                   Wp1rel, Wp1root, Wp2, x, xb, (long long)N * 16);
    p1_hist<<<B1, 1024, 0, stream>>>(ei_raw, flag, (int*)csr, E, C, B1);
    scan_k1<<<nbM, 1024, 0, stream>>>((int*)csr, off, bsums, M);
    scan_k2<<<1, 1024, 0, stream>>>(bsums, nbM);
    p3_scatter<<<B1, 1024, 0, stream>>>(ei_raw, flag, ea, off, bsums, part, E, C, B1);
    p4_build<<<C, 256, 0, stream>>>(off, bsums, part, csr, deg, base, E, N, C, B1);

    gather1<<<2048, 256, 0, stream>>>(xb, csr, base, deg, aggb, N);
    node_mfma<<<(N + 63) / 64, 256, 0, stream>>>(aggb, xb, Wp1rel, Wp1root, Wp2,
                                                 brel1, brel2, hrb, hro, N);
    gather2<<<2048, 256, 0, stream>>>(hrb, hro, csr, base, deg, out, N);
}